// Round 1
// baseline (3765.300 us; speedup 1.0000x reference)
//
// LunarisCodex MoE-GPT forward, MI355X/gfx950.
// Precision plan: all compute upstream of MoE gates in f32 (routing argmax must
// match the f32 reference exactly); only the final logits GEMM uses bf16 MFMA.
// ws requirement: ~350 MB.
#include <hip/hip_runtime.h>

typedef __attribute__((ext_vector_type(8))) short short8;
typedef __attribute__((ext_vector_type(4))) float f32x4;

constexpr int Bc = 2, Tc = 1024, Dc = 768, NHc = 12, HDc = 64;
constexpr int Vc = 50257, Lc = 2, Ec = 8, Hc = 2048;
constexpr int Ntok = Bc * Tc;            // 2048
constexpr int CAPc = 320, CAPPc = 384;   // capacity, padded rows per expert
constexpr long long LOGITS_N = (long long)Bc * Tc * Vc;  // 102926336

__device__ __forceinline__ unsigned short f32_to_bf16(float f) {
  unsigned int u = __float_as_uint(f);
  unsigned int r = (u + 0x7FFFu + ((u >> 16) & 1u)) >> 16;   // RNE
  return (unsigned short)r;
}

// ---------------- small kernels ----------------

__global__ void zero_small(float* psum, float* z2) {
  int t = threadIdx.x;
  if (t < Lc * Ec) psum[t] = 0.f;
  if (t < Lc) z2[t] = 0.f;
}

__global__ void embed_k(const int* __restrict__ idx, const float* __restrict__ wte,
                        float* __restrict__ x) {
  int n = blockIdx.x;
  long long v = idx[n];
  const float4* src = (const float4*)(wte + v * 768);
  float4* dst = (float4*)(x + (long long)n * 768);
  int t = threadIdx.x;
  if (t < 192) dst[t] = src[t];
}

__global__ void f2bf4(const float* __restrict__ in, unsigned short* __restrict__ out,
                      long long n4) {
  long long i = (long long)blockIdx.x * 256 + threadIdx.x;
  if (i >= n4) return;
  float4 v = ((const float4*)in)[i];
  ushort4 o;
  o.x = f32_to_bf16(v.x); o.y = f32_to_bf16(v.y);
  o.z = f32_to_bf16(v.z); o.w = f32_to_bf16(v.w);
  ((ushort4*)out)[i] = o;
}

// rmsnorm over 768 cols; supports strided in/out (q,k live inside qkv rows)
__global__ void __launch_bounds__(256) rmsnorm_k(const float* in, int istride,
                                                 float* outp, int ostride,
                                                 const float* w) {
  long long n = blockIdx.x;
  const float* xr = in + n * istride;
  float* yr = outp + n * ostride;
  int tid = threadIdx.x;
  float s = 0.f;
  for (int i = tid; i < 768; i += 256) { float v = xr[i]; s += v * v; }
  #pragma unroll
  for (int o = 32; o; o >>= 1) s += __shfl_down(s, o);
  __shared__ float red[4];
  __shared__ float bs;
  if ((tid & 63) == 0) red[tid >> 6] = s;
  __syncthreads();
  if (tid == 0) bs = rsqrtf((red[0] + red[1] + red[2] + red[3]) / 768.0f + 1e-5f);
  __syncthreads();
  float sc = bs;
  for (int i = tid; i < 768; i += 256) yr[i] = xr[i] * sc * w[i];
}

// qkv (N,2304) -> q_r,k_r,v_r (B,NH,T,64) with RoPE on q,k
__global__ void __launch_bounds__(256) rope_split(const float* __restrict__ qkv,
    float* __restrict__ qr, float* __restrict__ kr, float* __restrict__ vr) {
  int i = blockIdx.x * 256 + threadIdx.x;   // < Ntok*12*32
  int j = i & 31;
  int hh = (i >> 5) % 12;
  int n = i / (32 * 12);
  int t = n & 1023;
  float fr = powf(10000.0f, -((float)(2 * j) * (1.0f / 64.0f)));
  float ang = (float)t * fr;
  float c = cosf(ang), s = sinf(ang);
  const float* bp = qkv + (long long)n * 2304 + hh * 64 + 2 * j;
  long long o = (((long long)((n >> 10) * 12 + hh)) * 1024 + t) * 64 + 2 * j;
  float q0 = bp[0], q1 = bp[1];
  qr[o] = q0 * c - q1 * s;  qr[o + 1] = q0 * s + q1 * c;
  float k0 = bp[768], k1 = bp[769];
  kr[o] = k0 * c - k1 * s;  kr[o + 1] = k0 * s + k1 * c;
  vr[o] = bp[1536];         vr[o + 1] = bp[1537];
}

// in-place causal softmax over rows of (z,T,T); scale 1/8 applied here
__global__ void __launch_bounds__(256) softmax_causal(float* sp) {
  int i = blockIdx.x;
  long long z = blockIdx.y;
  float* row = sp + z * (long long)Tc * Tc + (long long)i * Tc;
  int nv = i + 1;
  __shared__ float buf[1024];
  __shared__ float red[4];
  __shared__ float bval;
  int tid = threadIdx.x;
  float mx = -3.4e38f;
  for (int j = tid; j < nv; j += 256) { float v = row[j] * 0.125f; buf[j] = v; mx = fmaxf(mx, v); }
  #pragma unroll
  for (int o = 32; o; o >>= 1) mx = fmaxf(mx, __shfl_down(mx, o));
  if ((tid & 63) == 0) red[tid >> 6] = mx;
  __syncthreads();
  if (tid == 0) bval = fmaxf(fmaxf(red[0], red[1]), fmaxf(red[2], red[3]));
  __syncthreads();
  float m = bval;
  float s = 0.f;
  for (int j = tid; j < nv; j += 256) { float p = expf(buf[j] - m); buf[j] = p; s += p; }
  #pragma unroll
  for (int o = 32; o; o >>= 1) s += __shfl_down(s, o);
  if ((tid & 63) == 0) red[tid >> 6] = s;
  __syncthreads();
  if (tid == 0) bval = red[0] + red[1] + red[2] + red[3];
  __syncthreads();
  float den = bval;
  for (int j = tid; j < nv; j += 256) row[j] = buf[j] / den;
  for (int j = nv + tid; j < Tc; j += 256) row[j] = 0.f;
}

// gate: logits(f32), softmax probs, argmax (first-max), aux accumulators
__global__ void __launch_bounds__(256) gate_k(const float* __restrict__ xin,
    const float* __restrict__ gw, int* __restrict__ top,
    float* __restrict__ psum, float* __restrict__ z2) {
  __shared__ float gws[768 * 8];
  __shared__ float pacc[8];
  __shared__ float zacc;
  int tid = threadIdx.x;
  for (int i = tid; i < 768 * 8 / 4; i += 256) ((float4*)gws)[i] = ((const float4*)gw)[i];
  if (tid < 8) pacc[tid] = 0.f;
  if (tid == 0) zacc = 0.f;
  __syncthreads();
  int n = blockIdx.x * 256 + tid;
  const float4* xr4 = (const float4*)(xin + (long long)n * 768);
  float l[8] = {0, 0, 0, 0, 0, 0, 0, 0};
  for (int d4 = 0; d4 < 192; ++d4) {
    float4 xv = xr4[d4];
    const float* g = &gws[d4 * 32];
    #pragma unroll
    for (int e = 0; e < 8; ++e)
      l[e] += xv.x * g[e] + xv.y * g[8 + e] + xv.z * g[16 + e] + xv.w * g[24 + e];
  }
  float mx = l[0]; int bi = 0;
  #pragma unroll
  for (int e = 1; e < 8; ++e) if (l[e] > mx) { mx = l[e]; bi = e; }  // first-max
  float p[8]; float se = 0.f;
  #pragma unroll
  for (int e = 0; e < 8; ++e) { p[e] = expf(l[e] - mx); se += p[e]; }
  float z = mx + logf(se);
  top[n] = bi;
  #pragma unroll
  for (int e = 0; e < 8; ++e) atomicAdd(&pacc[e], p[e] / se);
  atomicAdd(&zacc, z * z);
  __syncthreads();
  if (tid < 8) atomicAdd(&psum[tid], pacc[tid]);
  if (tid == 0) atomicAdd(z2, zacc);
}

// single-wave sequential-by-construction rank scan (matches stable argsort)
__global__ void route_scan(const int* __restrict__ top, int* __restrict__ rank,
                           int* __restrict__ cnt) {
  int lane = threadIdx.x;
  int c[8] = {0, 0, 0, 0, 0, 0, 0, 0};
  unsigned long long below = (1ull << lane) - 1ull;
  for (int s = 0; s < Ntok / 64; ++s) {
    int n = s * 64 + lane;
    int e = top[n];
    int r = 0;
    #pragma unroll
    for (int q = 0; q < 8; ++q) {
      unsigned long long m = __ballot(e == q);
      if (e == q) r = c[q] + __popcll(m & below);
      c[q] += __popcll(m);
    }
    rank[n] = r;
  }
  #pragma unroll
  for (int q = 0; q < 8; ++q) if (lane == q) cnt[q] = c[q];
}

__global__ void scatter_xb(const float* __restrict__ xin, const int* __restrict__ top,
                           const int* __restrict__ rank, float* __restrict__ xb) {
  int n = blockIdx.x;
  int r = rank[n];
  if (r >= CAPc) return;            // dropped token
  int e = top[n];
  const float4* src = (const float4*)(xin + (long long)n * 768);
  float4* dst = (float4*)(xb + ((long long)e * CAPPc + r) * 768);
  int t = threadIdx.x;
  if (t < 192) dst[t] = src[t];
}

__global__ void __launch_bounds__(256) silu_k(const float* __restrict__ gu,
                                              float* __restrict__ act) {
  long long i = (long long)blockIdx.x * 256 + threadIdx.x;  // < E*CAPP*H
  long long row = i >> 11;
  int h = (int)(i & 2047);
  float g = gu[row * 4096 + h];
  float u = gu[row * 4096 + 2048 + h];
  act[i] = g / (1.f + expf(-g)) * u;
}

__global__ void gather_add(const float* __restrict__ h, const float* __restrict__ yexp,
                           const int* __restrict__ top, const int* __restrict__ rank,
                           float* __restrict__ xo) {
  int n = blockIdx.x;
  int r = rank[n], e = top[n];
  bool kept = r < CAPc;
  int rc = kept ? r : (CAPc - 1);
  const float4* hs = (const float4*)(h + (long long)n * 768);
  const float4* ys = (const float4*)(yexp + ((long long)e * CAPPc + rc) * 768);
  float4* dst = (float4*)(xo + (long long)n * 768);
  int t = threadIdx.x;
  if (t < 192) {
    float4 v = hs[t];
    if (kept) { float4 y = ys[t]; v.x += y.x; v.y += y.y; v.z += y.z; v.w += y.w; }
    dst[t] = v;
  }
}

__global__ void aux_fin(const float* __restrict__ psum, const int* __restrict__ cnt,
                        const float* __restrict__ z2, float* __restrict__ outp) {
  if (threadIdx.x == 0) {
    float aux = 0.f;
    for (int l = 0; l < Lc; ++l) {
      float bl = 0.f;
      for (int e = 0; e < 8; ++e)
        bl += (psum[l * 8 + e] * (1.0f / 2048.0f)) * ((float)cnt[l * 8 + e] * (1.0f / 2048.0f));
      aux += bl * (0.01f * 8.0f) + (z2[l] * (1.0f / 2048.0f)) * 0.001f;
    }
    outp[0] = aux;
  }
}

// ---------------- f32 GEMM (vector ALU, upstream-of-gate precision) ----------------
// C(M,N) = A(M,K) @ B  [+Add].  BT=0: B is (K,N); BT=1: B is (N,K) row-major.
// Batched over grid.z: A += z*sA, B += z*sB, C/Add += (z/zdiv)*sC1 + (z%zdiv)*sC2.
// Requires M%BM==0, N%BN==0, K%BK==0 (true for all uses here).
template <int BM, int BN, int BK, int TM, int TN, int BT, int ADD>
__global__ void __launch_bounds__(256) gemm_f32(
    const float* A, const float* B, float* C, const float* Add,
    int M, int N, int K,
    long long sA, long long sB, int zdiv, long long sC1, long long sC2,
    int ldc, int causal) {
  constexpr int NTX = BN / TN, NTY = BM / TM;
  static_assert(NTX * NTY == 256, "block must be 256 threads");
  constexpr int ASTR = BK + 4;
  constexpr int BSR = BT ? BN : BK;
  constexpr int BSC = BT ? (BK + 4) : BN;
  __shared__ float As[BM][ASTR];
  __shared__ float Bs[BSR][BSC];
  const int z = blockIdx.z;
  A += (long long)z * sA;
  B += (long long)z * sB;
  const long long co = (long long)(z / zdiv) * sC1 + (long long)(z % zdiv) * sC2;
  C += co;
  if (ADD) Add += co;
  const int m0 = blockIdx.y * BM, n0 = blockIdx.x * BN;
  if (causal && n0 > m0 + BM - 1) return;   // strictly-upper causal tile
  const int tid = threadIdx.x;
  const int tx = tid % NTX, ty = tid / NTX;
  float acc[TM][TN] = {};
  for (int k0 = 0; k0 < K; k0 += BK) {
    for (int i = tid * 4; i < BM * BK; i += 1024) {
      int r = i / BK, c = i % BK;
      *(float4*)&As[r][c] = *(const float4*)(A + (long long)(m0 + r) * K + k0 + c);
    }
    if constexpr (BT) {
      for (int i = tid * 4; i < BN * BK; i += 1024) {
        int r = i / BK, c = i % BK;
        *(float4*)&Bs[r][c] = *(const float4*)(B + (long long)(n0 + r) * K + k0 + c);
      }
    } else {
      for (int i = tid * 4; i < BK * BN; i += 1024) {
        int r = i / BN, c = i % BN;
        *(float4*)&Bs[r][c] = *(const float4*)(B + (long long)(k0 + r) * N + n0 + c);
      }
    }
    __syncthreads();
    #pragma unroll
    for (int kk = 0; kk < BK; kk += 4) {
      float4 av[TM];
      #pragma unroll
      for (int i = 0; i < TM; ++i) av[i] = *(const float4*)&As[ty * TM + i][kk];
      if constexpr (BT) {
        #pragma unroll
        for (int jv = 0; jv < TN; ++jv) {
          float4 bv = *(const float4*)&Bs[tx * TN + jv][kk];
          #pragma unroll
          for (int i = 0; i < TM; ++i)
            acc[i][jv] += av[i].x * bv.x + av[i].y * bv.y + av[i].z * bv.z + av[i].w * bv.w;
        }
      } else {
        float4 bv[4][TN / 4];
        #pragma unroll
        for (int kq = 0; kq < 4; ++kq)
          #pragma unroll
          for (int jj = 0; jj < TN / 4; ++jj)
            bv[kq][jj] = *(const float4*)&Bs[kk + kq][tx * TN + jj * 4];
        #pragma unroll
        for (int i = 0; i < TM; ++i) {
          float a0 = av[i].x, a1 = av[i].y, a2 = av[i].z, a3 = av[i].w;
          #pragma unroll
          for (int jj = 0; jj < TN / 4; ++jj) {
            acc[i][jj * 4 + 0] += a0 * bv[0][jj].x + a1 * bv[1][jj].x + a2 * bv[2][jj].x + a3 * bv[3][jj].x;
            acc[i][jj * 4 + 1] += a0 * bv[0][jj].y + a1 * bv[1][jj].y + a2 * bv[2][jj].y + a3 * bv[3][jj].y;
            acc[i][jj * 4 + 2] += a0 * bv[0][jj].z + a1 * bv[1][jj].z + a2 * bv[2][jj].z + a3 * bv[3][jj].z;
            acc[i][jj * 4 + 3] += a0 * bv[0][jj].w + a1 * bv[1][jj].w + a2 * bv[2][jj].w + a3 * bv[3][jj].w;
          }
        }
      }
    }
    __syncthreads();
  }
  #pragma unroll
  for (int i = 0; i < TM; ++i) {
    long long r = m0 + ty * TM + i;
    #pragma unroll
    for (int jj = 0; jj < TN / 4; ++jj) {
      long long c = n0 + tx * TN + jj * 4;
      float4 v = make_float4(acc[i][jj * 4], acc[i][jj * 4 + 1], acc[i][jj * 4 + 2], acc[i][jj * 4 + 3]);
      if (ADD) {
        float4 a = *(const float4*)(Add + r * ldc + c);
        v.x += a.x; v.y += a.y; v.z += a.z; v.w += a.w;
      }
      *(float4*)(C + r * ldc + c) = v;
    }
  }
}

// ---------------- bf16 MFMA GEMM for final logits ----------------
// C(M,N) f32 = A(M,K)bf16 @ Bt(N,K)bf16^T. 128x128 tile, BK=32, 4 waves (2x2),
// each wave 4x4 accs of 16x16x32. Fragment layouts per guide §3 (verified m89/m91).
__global__ void __launch_bounds__(256) gemm_bf16_bt(
    const unsigned short* __restrict__ A, const unsigned short* __restrict__ Bt,
    float* __restrict__ C, int M, int N, int K, int ldc) {
  __shared__ __align__(16) unsigned short As[128 * 32];
  __shared__ __align__(16) unsigned short Bs[128 * 32];
  const int tid = threadIdx.x;
  const int lane = tid & 63, wave = tid >> 6;
  const int wm = wave >> 1, wn = wave & 1;
  const int m0 = blockIdx.y * 128, n0 = blockIdx.x * 128;
  f32x4 acc[4][4];
  #pragma unroll
  for (int m = 0; m < 4; ++m)
    #pragma unroll
    for (int n = 0; n < 4; ++n) acc[m][n] = (f32x4){0.f, 0.f, 0.f, 0.f};
  for (int k0 = 0; k0 < K; k0 += 32) {
    #pragma unroll
    for (int r = 0; r < 2; ++r) {
      int off = tid * 8 + r * 2048;
      int row = off >> 5, col = off & 31;
      *(uint4*)&As[off] = *(const uint4*)(A + (long long)(m0 + row) * K + k0 + col);
      int brow = n0 + row; if (brow > N - 1) brow = N - 1;   // clamp N tail
      *(uint4*)&Bs[off] = *(const uint4*)(Bt + (long long)brow * K + k0 + col);
    }
    __syncthreads();
    short8 bf[4];
    #pragma unroll
    for (int n = 0; n < 4; ++n)
      bf[n] = *(const short8*)&Bs[(wn * 64 + n * 16 + (lane & 15)) * 32 + (lane >> 4) * 8];
    #pragma unroll
    for (int m = 0; m < 4; ++m) {
      short8 af = *(const short8*)&As[(wm * 64 + m * 16 + (lane & 15)) * 32 + (lane >> 4) * 8];
      #pragma unroll
      for (int n = 0; n < 4; ++n)
        acc[m][n] = __builtin_amdgcn_mfma_f32_16x16x32_bf16(af, bf[n], acc[m][n], 0, 0, 0);
    }
    __syncthreads();
  }
  const int rb = m0 + wm * 64, cb = n0 + wn * 64;
  #pragma unroll
  for (int m = 0; m < 4; ++m)
    #pragma unroll
    for (int n = 0; n < 4; ++n) {
      int col = cb + n * 16 + (lane & 15);
      if (col < N) {
        #pragma unroll
        for (int j = 0; j < 4; ++j) {
          int row = rb + m * 16 + (lane >> 4) * 4 + j;
          C[(long long)row * ldc + col] = acc[m][n][j];
        }
      }
    }
}

// ---------------- host launch ----------------

extern "C" void kernel_launch(void* const* d_in, const int* in_sizes, int n_in,
                              void* d_out, int out_size, void* d_ws, size_t ws_size,
                              hipStream_t stream) {
  (void)in_sizes; (void)n_in; (void)out_size; (void)ws_size;
  const int*   idx   = (const int*)d_in[0];
  const float* wte   = (const float*)d_in[1];
  const float* wqkv  = (const float*)d_in[2];
  const float* qnw   = (const float*)d_in[3];
  const float* knw   = (const float*)d_in[4];
  const float* oproj = (const float*)d_in[5];
  const float* ffnw  = (const float*)d_in[6];
  const float* gatew = (const float*)d_in[7];
  const float* w13   = (const float*)d_in[8];
  const float* w2p   = (const float*)d_in[9];
  const float* lnf   = (const float*)d_in[10];
  float* out = (float*)d_out;

  char* base = (char*)d_ws;
  size_t off = 0;
  auto alloc = [&](size_t bytes) -> char* {
    off = (off + 255) & ~(size_t)255;
    char* p = base + off; off += bytes; return p;
  };
  float* x    = (float*)alloc((size_t)Ntok * Dc * 4);
  float* qkv  = (float*)alloc((size_t)Ntok * 3 * Dc * 4);
  float* qr   = (float*)alloc((size_t)Ntok * Dc * 4);
  float* kr   = (float*)alloc((size_t)Ntok * Dc * 4);
  float* vr   = (float*)alloc((size_t)Ntok * Dc * 4);
  float* sp   = (float*)alloc((size_t)Bc * NHc * Tc * Tc * 4);   // 100.7 MB
  float* yfl  = (float*)alloc((size_t)Ntok * Dc * 4);
  float* hbuf = (float*)alloc((size_t)Ntok * Dc * 4);
  float* ffn  = (float*)alloc((size_t)Ntok * Dc * 4);
  float* xb   = (float*)alloc((size_t)Ec * CAPPc * Dc * 4);
  float* gu   = (float*)alloc((size_t)Ec * CAPPc * 2 * Hc * 4);  // 50.3 MB
  float* act  = (float*)alloc((size_t)Ec * CAPPc * Hc * 4);
  float* yexp = (float*)alloc((size_t)Ec * CAPPc * Dc * 4);
  float* xf   = (float*)alloc((size_t)Ntok * Dc * 4);
  unsigned short* wte16 = (unsigned short*)alloc((size_t)Vc * Dc * 2);  // 77.2 MB
  unsigned short* xf16  = (unsigned short*)alloc((size_t)Ntok * Dc * 2);
  int* top    = (int*)alloc(Ntok * 4);
  int* rankb  = (int*)alloc(Ntok * 4);
  int* cnt    = (int*)alloc(Lc * Ec * 4);
  float* psum = (float*)alloc(Lc * Ec * 4);
  float* z2   = (float*)alloc(Lc * 4);

  zero_small<<<1, 64, 0, stream>>>(psum, z2);
  f2bf4<<<(int)(((long long)Vc * Dc / 4 + 255) / 256), 256, 0, stream>>>(
      wte, wte16, (long long)Vc * Dc / 4);
  embed_k<<<Ntok, 192, 0, stream>>>(idx, wte, x);

  for (int l = 0; l < Lc; ++l) {
    // qkv = x @ wqkv[l]   (2048,768)@(768,2304)
    gemm_f32<128, 128, 16, 8, 8, 0, 0><<<dim3(3 * Dc / 128, Ntok / 128, 1), 256, 0, stream>>>(
        x, wqkv + (size_t)l * Dc * 3 * Dc, qkv, nullptr, Ntok, 3 * Dc, Dc,
        0LL, 0LL, 1, 0LL, 0LL, 3 * Dc, 0);
    rmsnorm_k<<<Ntok, 256, 0, stream>>>(qkv,      3 * Dc, qkv,      3 * Dc, qnw + l * Dc);
    rmsnorm_k<<<Ntok, 256, 0, stream>>>(qkv + Dc, 3 * Dc, qkv + Dc, 3 * Dc, knw + l * Dc);
    rope_split<<<(Ntok * NHc * 32) / 256, 256, 0, stream>>>(qkv, qr, kr, vr);
    // scores = q @ k^T per (b,h); causal tiles only
    gemm_f32<64, 64, 32, 4, 4, 1, 0><<<dim3(Tc / 64, Tc / 64, Bc * NHc), 256, 0, stream>>>(
        qr, kr, sp, nullptr, Tc, Tc, HDc,
        (long long)Tc * HDc, (long long)Tc * HDc, 1, (long long)Tc * Tc, 0LL, Tc, 1);
    softmax_causal<<<dim3(Tc, Bc * NHc), 256, 0, stream>>>(sp);
    // y = P @ V  -> written directly into flat (B,T,D) layout at col h*64
    gemm_f32<64, 64, 32, 4, 4, 0, 0><<<dim3(1, Tc / 64, Bc * NHc), 256, 0, stream>>>(
        sp, vr, yfl, nullptr, Tc, HDc, Tc,
        (long long)Tc * Tc, (long long)Tc * HDc, NHc, (long long)Tc * Dc, 64LL, Dc, 0);
    // h = x + y @ o_proj[l]
    gemm_f32<128, 128, 16, 8, 8, 0, 1><<<dim3(Dc / 128, Ntok / 128, 1), 256, 0, stream>>>(
        yfl, oproj + (size_t)l * Dc * Dc, hbuf, x, Ntok, Dc, Dc,
        0LL, 0LL, 1, 0LL, 0LL, Dc, 0);
    rmsnorm_k<<<Ntok, 256, 0, stream>>>(hbuf, Dc, ffn, Dc, ffnw + l * Dc);
    gate_k<<<Ntok / 256, 256, 0, stream>>>(ffn, gatew + (size_t)l * Dc * Ec, top,
                                           psum + l * Ec, z2 + l);
    route_scan<<<1, 64, 0, stream>>>(top, rankb, cnt + l * Ec);
    scatter_xb<<<Ntok, 192, 0, stream>>>(ffn, top, rankb, xb);
    // gu = xb @ w13[l]  (per-expert 384x768 @ 768x4096)
    gemm_f32<128, 128, 16, 8, 8, 0, 0><<<dim3(2 * Hc / 128, CAPPc / 128, Ec), 256, 0, stream>>>(
        xb, w13 + (size_t)l * Ec * Dc * 2 * Hc, gu, nullptr, CAPPc, 2 * Hc, Dc,
        (long long)CAPPc * Dc, (long long)Dc * 2 * Hc, 1, (long long)CAPPc * 2 * Hc, 0LL,
        2 * Hc, 0);
    silu_k<<<(Ec * CAPPc * Hc) / 256, 256, 0, stream>>>(gu, act);
    // yexp = act @ w2[l]  (per-expert 384x2048 @ 2048x768)
    gemm_f32<128, 128, 16, 8, 8, 0, 0><<<dim3(Dc / 128, CAPPc / 128, Ec), 256, 0, stream>>>(
        act, w2p + (size_t)l * Ec * Hc * Dc, yexp, nullptr, CAPPc, Dc, Hc,
        (long long)CAPPc * Hc, (long long)Hc * Dc, 1, (long long)CAPPc * Dc, 0LL, Dc, 0);
    gather_add<<<Ntok, 192, 0, stream>>>(hbuf, yexp, top, rankb, x);
  }

  rmsnorm_k<<<Ntok, 256, 0, stream>>>(x, Dc, xf, Dc, lnf);
  f2bf4<<<((Ntok * Dc / 4) + 255) / 256, 256, 0, stream>>>(xf, xf16, (long long)Ntok * Dc / 4);
  gemm_bf16_bt<<<dim3((Vc + 127) / 128, Ntok / 128, 1), 256, 0, stream>>>(
      xf16, wte16, out, Ntok, Vc, Dc, Vc);
  aux_fin<<<1, 64, 0, stream>>>(psum, cnt, z2, out + LOGITS_N);
}

// Round 2
// 1716.128 us; speedup vs baseline: 2.1941x; 2.1941x over previous
//
// LunarisCodex MoE-GPT forward, MI355X/gfx950. Round 2: all GEMMs on MFMA.
// Precision: split-fp16 x3 product (err ~2e-7/elem) upstream so MoE argmax
// matches f32 reference; logits = single fp16 MFMA (err ~3e-4 << 0.0687).
// ws ~342 MB (round 1 proved >=344.6 available). Aliases: sp ⊃ {gu, act16,
// wq16, yexp}; w13_16 ⊃ wte16 (wte converted after last w13 use).
#include <hip/hip_runtime.h>

typedef __attribute__((ext_vector_type(8))) _Float16 half8;
typedef __attribute__((ext_vector_type(4))) float f32x4;

constexpr int Bc = 2, Tc = 1024, Dc = 768, NHc = 12, HDc = 64;
constexpr int Vc = 50257, Lc = 2, Ec = 8, Hc = 2048;
constexpr int Ntok = Bc * Tc;            // 2048
constexpr int CAPc = 320, CAPPc = 384;   // capacity, padded rows per expert
constexpr long long LOGITS_N = (long long)Bc * Tc * Vc;  // 102926336

__device__ __forceinline__ void splitf16(float a, unsigned short& h, unsigned short& l) {
  _Float16 hh = (_Float16)a;                       // RNE
  _Float16 ll = (_Float16)(a - (float)hh);
  h = __builtin_bit_cast(unsigned short, hh);
  l = __builtin_bit_cast(unsigned short, ll);
}
__device__ __forceinline__ unsigned short f16o(float a) {
  _Float16 hh = (_Float16)a;
  return __builtin_bit_cast(unsigned short, hh);
}

// ---------------- small kernels ----------------

__global__ void zero_small(float* psum, float* z2) {
  int t = threadIdx.x;
  if (t < Lc * Ec) psum[t] = 0.f;
  if (t < Lc) z2[t] = 0.f;
}

__global__ void embed_k(const int* __restrict__ idx, const float* __restrict__ wte,
                        float* __restrict__ x) {
  int n = blockIdx.x;
  long long v = idx[n];
  const float4* src = (const float4*)(wte + v * 768);
  float4* dst = (float4*)(x + (long long)n * 768);
  int t = threadIdx.x;
  if (t < 192) dst[t] = src[t];
}

// f32 -> fp16 single (for wte)
__global__ void f2h4(const float* __restrict__ in, unsigned short* __restrict__ out,
                     long long n4) {
  long long i = (long long)blockIdx.x * 256 + threadIdx.x;
  if (i >= n4) return;
  float4 v = ((const float4*)in)[i];
  ushort4 o;
  o.x = f16o(v.x); o.y = f16o(v.y); o.z = f16o(v.z); o.w = f16o(v.w);
  ((ushort4*)out)[i] = o;
}

// f32 (R,K) -> fp16 split (R,2K) [hi K | lo K]
__global__ void __launch_bounds__(256) split2_rows(const float* __restrict__ src,
    unsigned short* __restrict__ dst, int K, long long total4) {
  long long i = (long long)blockIdx.x * 256 + threadIdx.x;
  if (i >= total4) return;
  int kq = (int)(i % (K / 4)) * 4;
  long long row = i / (K / 4);
  float4 v = *(const float4*)(src + row * K + kq);
  ushort4 h, l;
  splitf16(v.x, h.x, l.x); splitf16(v.y, h.y, l.y);
  splitf16(v.z, h.z, l.z); splitf16(v.w, h.w, l.w);
  unsigned short* d = dst + row * 2 * K + kq;
  *(ushort4*)d = h;
  *(ushort4*)(d + K) = l;
}

// f32 weights (K,N) -> fp16 split transposed (N,2K) [hi K | lo K], batched over z
__global__ void __launch_bounds__(256) split2_wT(const float* __restrict__ src,
    unsigned short* __restrict__ dst, int K, int N, long long sS, long long sD) {
  __shared__ float t[32][33];
  int z = blockIdx.z;
  src += (long long)z * sS;
  dst += (long long)z * sD;
  int n0 = blockIdx.x * 32, k0 = blockIdx.y * 32;
  int tid = threadIdx.x;
  int r = tid >> 3, c4 = (tid & 7) * 4;
  float4 v = *(const float4*)(src + (long long)(k0 + r) * N + n0 + c4);
  t[r][c4 + 0] = v.x; t[r][c4 + 1] = v.y; t[r][c4 + 2] = v.z; t[r][c4 + 3] = v.w;
  __syncthreads();
  int n = tid >> 3, kq = (tid & 7) * 4;
  ushort4 h, l;
  splitf16(t[kq + 0][n], h.x, l.x);
  splitf16(t[kq + 1][n], h.y, l.y);
  splitf16(t[kq + 2][n], h.z, l.z);
  splitf16(t[kq + 3][n], h.w, l.w);
  unsigned short* d = dst + (long long)(n0 + n) * 2 * K + k0 + kq;
  *(ushort4*)d = h;
  *(ushort4*)(d + K) = l;
}

// rmsnorm over 768 cols; strided in/out (q,k live inside qkv rows), f32 out
__global__ void __launch_bounds__(256) rmsnorm_k(const float* in, int istride,
                                                 float* outp, int ostride,
                                                 const float* w) {
  long long n = blockIdx.x;
  const float* xr = in + n * istride;
  float* yr = outp + n * ostride;
  int tid = threadIdx.x;
  float s = 0.f;
  for (int i = tid; i < 768; i += 256) { float v = xr[i]; s += v * v; }
  #pragma unroll
  for (int o = 32; o; o >>= 1) s += __shfl_down(s, o);
  __shared__ float red[4];
  __shared__ float bs;
  if ((tid & 63) == 0) red[tid >> 6] = s;
  __syncthreads();
  if (tid == 0) bs = rsqrtf((red[0] + red[1] + red[2] + red[3]) / 768.0f + 1e-5f);
  __syncthreads();
  float sc = bs;
  for (int i = tid; i < 768; i += 256) yr[i] = xr[i] * sc * w[i];
}

// rmsnorm -> fp16 single output (final ln before logits)
__global__ void __launch_bounds__(256) rmsnorm_h(const float* in,
                                                 unsigned short* outp, const float* w) {
  long long n = blockIdx.x;
  const float* xr = in + n * 768;
  unsigned short* yr = outp + n * 768;
  int tid = threadIdx.x;
  float s = 0.f;
  for (int i = tid; i < 768; i += 256) { float v = xr[i]; s += v * v; }
  #pragma unroll
  for (int o = 32; o; o >>= 1) s += __shfl_down(s, o);
  __shared__ float red[4];
  __shared__ float bs;
  if ((tid & 63) == 0) red[tid >> 6] = s;
  __syncthreads();
  if (tid == 0) bs = rsqrtf((red[0] + red[1] + red[2] + red[3]) / 768.0f + 1e-5f);
  __syncthreads();
  float sc = bs;
  for (int i = tid; i < 768; i += 256) yr[i] = f16o(xr[i] * sc * w[i]);
}

// qkv (N,2304) f32 -> split-fp16 qr,kr (z,1024,128=[hi64|lo64]) with RoPE,
// and V transposed vr (z,64,2048=[hi 1024 | lo 1024])
__global__ void __launch_bounds__(256) rope_split(const float* __restrict__ qkv,
    unsigned short* __restrict__ qr, unsigned short* __restrict__ kr,
    unsigned short* __restrict__ vr) {
  int i = blockIdx.x * 256 + threadIdx.x;   // < Ntok*12*32
  int j = i & 31;
  int hh = (i >> 5) % 12;
  int n = i / (32 * 12);
  int t = n & 1023;
  float fr = powf(10000.0f, -((float)(2 * j) * (1.0f / 64.0f)));
  float ang = (float)t * fr;
  float c = cosf(ang), s = sinf(ang);
  const float* bp = qkv + (long long)n * 2304 + hh * 64 + 2 * j;
  int z = (n >> 10) * 12 + hh;
  long long qb = ((long long)z * 1024 + t) * 128 + 2 * j;
  unsigned short h0, l0, h1, l1;
  float q0 = bp[0], q1 = bp[1];
  splitf16(q0 * c - q1 * s, h0, l0);
  splitf16(q0 * s + q1 * c, h1, l1);
  *(unsigned int*)&qr[qb] = (unsigned)h0 | ((unsigned)h1 << 16);
  *(unsigned int*)&qr[qb + 64] = (unsigned)l0 | ((unsigned)l1 << 16);
  float k0 = bp[768], k1 = bp[769];
  splitf16(k0 * c - k1 * s, h0, l0);
  splitf16(k0 * s + k1 * c, h1, l1);
  *(unsigned int*)&kr[qb] = (unsigned)h0 | ((unsigned)h1 << 16);
  *(unsigned int*)&kr[qb + 64] = (unsigned)l0 | ((unsigned)l1 << 16);
  float v0 = bp[1536], v1 = bp[1537];
  splitf16(v0, h0, l0);
  splitf16(v1, h1, l1);
  long long vb = ((long long)z * 64 + 2 * j) * 2048 + t;
  vr[vb] = h0; vr[vb + 1024] = l0;
  vr[vb + 2048] = h1; vr[vb + 3072] = l1;
}

// causal softmax over rows of (z,T,T) f32; writes the row back IN PLACE as
// split-fp16 [hi 1024 | lo 1024] (same 4KB footprint) for the PV MFMA GEMM.
__global__ void __launch_bounds__(256) softmax_causal(float* sp) {
  int i = blockIdx.x;
  long long z = blockIdx.y;
  float* row = sp + z * (long long)Tc * Tc + (long long)i * Tc;
  int nv = i + 1;
  __shared__ float buf[1024];
  __shared__ float red[4];
  __shared__ float bval;
  int tid = threadIdx.x;
  float mx = -3.4e38f;
  for (int j = tid; j < nv; j += 256) { float v = row[j] * 0.125f; buf[j] = v; mx = fmaxf(mx, v); }
  #pragma unroll
  for (int o = 32; o; o >>= 1) mx = fmaxf(mx, __shfl_down(mx, o));
  if ((tid & 63) == 0) red[tid >> 6] = mx;
  __syncthreads();
  if (tid == 0) bval = fmaxf(fmaxf(red[0], red[1]), fmaxf(red[2], red[3]));
  __syncthreads();
  float m = bval;
  float s = 0.f;
  for (int j = tid; j < nv; j += 256) { float p = expf(buf[j] - m); buf[j] = p; s += p; }
  #pragma unroll
  for (int o = 32; o; o >>= 1) s += __shfl_down(s, o);
  if ((tid & 63) == 0) red[tid >> 6] = s;
  __syncthreads();
  if (tid == 0) bval = red[0] + red[1] + red[2] + red[3];
  __syncthreads();
  float den = bval;
  unsigned short* rowh = (unsigned short*)row;
  for (int j = tid; j < 1024; j += 256) {
    float p = (j < nv) ? buf[j] / den : 0.f;
    unsigned short h, l;
    splitf16(p, h, l);
    rowh[j] = h;
    rowh[1024 + j] = l;
  }
}

// gate: logits(f32), softmax probs, argmax (first-max), aux accumulators
__global__ void __launch_bounds__(256) gate_k(const float* __restrict__ xin,
    const float* __restrict__ gw, int* __restrict__ top,
    float* __restrict__ psum, float* __restrict__ z2) {
  __shared__ float gws[768 * 8];
  __shared__ float pacc[8];
  __shared__ float zacc;
  int tid = threadIdx.x;
  for (int i = tid; i < 768 * 8 / 4; i += 256) ((float4*)gws)[i] = ((const float4*)gw)[i];
  if (tid < 8) pacc[tid] = 0.f;
  if (tid == 0) zacc = 0.f;
  __syncthreads();
  int n = blockIdx.x * 256 + tid;
  const float4* xr4 = (const float4*)(xin + (long long)n * 768);
  float l[8] = {0, 0, 0, 0, 0, 0, 0, 0};
  for (int d4 = 0; d4 < 192; ++d4) {
    float4 xv = xr4[d4];
    const float* g = &gws[d4 * 32];
    #pragma unroll
    for (int e = 0; e < 8; ++e)
      l[e] += xv.x * g[e] + xv.y * g[8 + e] + xv.z * g[16 + e] + xv.w * g[24 + e];
  }
  float mx = l[0]; int bi = 0;
  #pragma unroll
  for (int e = 1; e < 8; ++e) if (l[e] > mx) { mx = l[e]; bi = e; }  // first-max
  float p[8]; float se = 0.f;
  #pragma unroll
  for (int e = 0; e < 8; ++e) { p[e] = expf(l[e] - mx); se += p[e]; }
  float z = mx + logf(se);
  top[n] = bi;
  #pragma unroll
  for (int e = 0; e < 8; ++e) atomicAdd(&pacc[e], p[e] / se);
  atomicAdd(&zacc, z * z);
  __syncthreads();
  if (tid < 8) atomicAdd(&psum[tid], pacc[tid]);
  if (tid == 0) atomicAdd(z2, zacc);
}

// single-wave rank scan (matches stable argsort arrival order)
__global__ void route_scan(const int* __restrict__ top, int* __restrict__ rank,
                           int* __restrict__ cnt) {
  int lane = threadIdx.x;
  int c[8] = {0, 0, 0, 0, 0, 0, 0, 0};
  unsigned long long below = (1ull << lane) - 1ull;
  for (int s = 0; s < Ntok / 64; ++s) {
    int n = s * 64 + lane;
    int e = top[n];
    int r = 0;
    #pragma unroll
    for (int q = 0; q < 8; ++q) {
      unsigned long long m = __ballot(e == q);
      if (e == q) r = c[q] + __popcll(m & below);
      c[q] += __popcll(m);
    }
    rank[n] = r;
  }
  #pragma unroll
  for (int q = 0; q < 8; ++q) if (lane == q) cnt[q] = c[q];
}

// ffn f32 -> xb16 split (E*384, 1536=[hi768|lo768])
__global__ void scatter_xb(const float* __restrict__ xin, const int* __restrict__ top,
                           const int* __restrict__ rank, unsigned short* __restrict__ xb) {
  int n = blockIdx.x;
  int r = rank[n];
  if (r >= CAPc) return;
  int e = top[n];
  int t = threadIdx.x;
  if (t >= 192) return;
  float4 v = ((const float4*)(xin + (long long)n * 768))[t];
  ushort4 h, l;
  splitf16(v.x, h.x, l.x); splitf16(v.y, h.y, l.y);
  splitf16(v.z, h.z, l.z); splitf16(v.w, h.w, l.w);
  unsigned short* dst = xb + ((long long)e * CAPPc + r) * 1536 + t * 4;
  *(ushort4*)dst = h;
  *(ushort4*)(dst + 768) = l;
}

// gu f32 (rows,4096=[g2048|u2048]) -> act16 split (rows, 4096=[hi2048|lo2048])
__global__ void __launch_bounds__(256) silu_k(const float* __restrict__ gu,
                                              unsigned short* __restrict__ act) {
  long long i = (long long)blockIdx.x * 256 + threadIdx.x;  // < E*CAPP*H
  long long row = i >> 11;
  int h = (int)(i & 2047);
  float g = gu[row * 4096 + h];
  float u = gu[row * 4096 + 2048 + h];
  float a = g / (1.f + expf(-g)) * u;
  unsigned short hh, ll;
  splitf16(a, hh, ll);
  act[row * 4096 + h] = hh;
  act[row * 4096 + 2048 + h] = ll;
}

__global__ void gather_add(const float* __restrict__ h, const float* __restrict__ yexp,
                           const int* __restrict__ top, const int* __restrict__ rank,
                           float* __restrict__ xo) {
  int n = blockIdx.x;
  int r = rank[n], e = top[n];
  bool kept = r < CAPc;
  int rc = kept ? r : (CAPc - 1);
  const float4* hs = (const float4*)(h + (long long)n * 768);
  const float4* ys = (const float4*)(yexp + ((long long)e * CAPPc + rc) * 768);
  float4* dst = (float4*)(xo + (long long)n * 768);
  int t = threadIdx.x;
  if (t < 192) {
    float4 v = hs[t];
    if (kept) { float4 y = ys[t]; v.x += y.x; v.y += y.y; v.z += y.z; v.w += y.w; }
    dst[t] = v;
  }
}

__global__ void aux_fin(const float* __restrict__ psum, const int* __restrict__ cnt,
                        const float* __restrict__ z2, float* __restrict__ outp) {
  if (threadIdx.x == 0) {
    float aux = 0.f;
    for (int l = 0; l < Lc; ++l) {
      float bl = 0.f;
      for (int e = 0; e < 8; ++e)
        bl += (psum[l * 8 + e] * (1.0f / 2048.0f)) * ((float)cnt[l * 8 + e] * (1.0f / 2048.0f));
      aux += bl * (0.01f * 8.0f) + (z2[l] * (1.0f / 2048.0f)) * 0.001f;
    }
    outp[0] = aux;
  }
}

// ---------------- fp16 MFMA GEMM ----------------
// C(M,N) f32 [+Add] = A @ Bt^T.  A:(M, lda) fp16, Bt:(N, lda) fp16 (pre-transposed).
// SPLIT=1: storage [hi K | lo K] (lda=2K); product = AhBh + AlBh + AhBl via
// k-offset remap over NS=3*(K/32) steps:  offA=(s<2n1? s : s-2n1)*32,
// offB=(s<n1? s : s-n1)*32.  SPLIT=0: plain fp16, lda=K.
// 1-D grid with XCD chunk swizzle; bx (fast) = m-tile, by = n-tile, z batch.
// C += (z/zdiv)*sC1 + (z%zdiv)*sC2.
template <int BN, int SPLIT, int ADD, int NTAIL, int CAUSAL>
__global__ void __launch_bounds__(256) gemm_h(
    const unsigned short* __restrict__ A, const unsigned short* __restrict__ Bt,
    float* __restrict__ C, const float* __restrict__ Add,
    int M, int N, int K, int ldc, int gx, int gy,
    long long sA, long long sB, int zdiv, long long sC1, long long sC2) {
  constexpr int FN = (BN == 128) ? 4 : 2;
  __shared__ __align__(16) unsigned short As[128 * 32];
  __shared__ __align__(16) unsigned short Bs[BN * 32];
  int tot = gridDim.x;
  int lin = blockIdx.x;
  if ((tot & 7) == 0) lin = (lin & 7) * (tot >> 3) + (lin >> 3);  // XCD chunking
  int pz = lin / (gx * gy);
  int r2 = lin - pz * (gx * gy);
  const int m0 = (r2 % gx) * 128, n0 = (r2 / gx) * BN;
  if (CAUSAL && n0 > m0 + 127) return;
  A += (long long)pz * sA;
  Bt += (long long)pz * sB;
  const long long co = (long long)(pz / zdiv) * sC1 + (long long)(pz % zdiv) * sC2;
  const int lda = SPLIT ? 2 * K : K;
  const int n1 = K / 32;
  const int NS = SPLIT ? 3 * n1 : n1;
  const int tid = threadIdx.x;
  const int lane = tid & 63, wave = tid >> 6;
  const int wm = (BN == 128) ? (wave >> 1) : (wave & 1);
  const int wn = (BN == 128) ? (wave & 1) : (wave >> 1);
  const int srow = tid >> 2, scol = (tid & 3) * 8;
  f32x4 acc[4][FN];
  #pragma unroll
  for (int m = 0; m < 4; ++m)
    #pragma unroll
    for (int n = 0; n < FN; ++n) acc[m][n] = (f32x4){0.f, 0.f, 0.f, 0.f};
  for (int s = 0; s < NS; ++s) {
    const int kA = (SPLIT && s >= 2 * n1) ? (s - 2 * n1) * 32 : s * 32;
    const int kB = (SPLIT && s >= n1) ? (s - n1) * 32 : s * 32;
    #pragma unroll
    for (int r = 0; r < 2; ++r)
      *(uint4*)&As[(srow + r * 64) * 32 + scol] =
          *(const uint4*)(A + (long long)(m0 + srow + r * 64) * lda + kA + scol);
    #pragma unroll
    for (int r = 0; r < BN / 64; ++r) {
      int brow = n0 + srow + r * 64;
      if (NTAIL) brow = min(brow, N - 1);
      *(uint4*)&Bs[(srow + r * 64) * 32 + scol] =
          *(const uint4*)(Bt + (long long)brow * lda + kB + scol);
    }
    __syncthreads();
    half8 bf[FN];
    #pragma unroll
    for (int n = 0; n < FN; ++n)
      bf[n] = *(const half8*)&Bs[(wn * (FN * 16) + n * 16 + (lane & 15)) * 32 + (lane >> 4) * 8];
    #pragma unroll
    for (int m = 0; m < 4; ++m) {
      half8 af = *(const half8*)&As[(wm * 64 + m * 16 + (lane & 15)) * 32 + (lane >> 4) * 8];
      #pragma unroll
      for (int n = 0; n < FN; ++n)
        acc[m][n] = __builtin_amdgcn_mfma_f32_16x16x32_f16(af, bf[n], acc[m][n], 0, 0, 0);
    }
    __syncthreads();
  }
  #pragma unroll
  for (int m = 0; m < 4; ++m)
    #pragma unroll
    for (int n = 0; n < FN; ++n) {
      int col = n0 + wn * (FN * 16) + n * 16 + (lane & 15);
      if (!NTAIL || col < N) {
        #pragma unroll
        for (int j = 0; j < 4; ++j) {
          long long row = m0 + wm * 64 + m * 16 + (lane >> 4) * 4 + j;
          long long o = co + row * ldc + col;
          float v = acc[m][n][j];
          if (ADD) v += Add[o];
          C[o] = v;
        }
      }
    }
}

// ---------------- host launch ----------------

extern "C" void kernel_launch(void* const* d_in, const int* in_sizes, int n_in,
                              void* d_out, int out_size, void* d_ws, size_t ws_size,
                              hipStream_t stream) {
  (void)in_sizes; (void)n_in; (void)out_size; (void)ws_size;
  const int*   idx   = (const int*)d_in[0];
  const float* wte   = (const float*)d_in[1];
  const float* wqkv  = (const float*)d_in[2];
  const float* qnw   = (const float*)d_in[3];
  const float* knw   = (const float*)d_in[4];
  const float* oproj = (const float*)d_in[5];
  const float* ffnw  = (const float*)d_in[6];
  const float* gatew = (const float*)d_in[7];
  const float* w13   = (const float*)d_in[8];
  const float* w2p   = (const float*)d_in[9];
  const float* lnf   = (const float*)d_in[10];
  float* out = (float*)d_out;

  char* base = (char*)d_ws;
  size_t off = 0;
  auto alloc = [&](size_t bytes) -> char* {
    off = (off + 255) & ~(size_t)255;
    char* p = base + off; off += bytes; return p;
  };
  float* x     = (float*)alloc((size_t)Ntok * 768 * 4);
  float* qkv   = (float*)alloc((size_t)Ntok * 2304 * 4);
  float* hbuf  = (float*)alloc((size_t)Ntok * 768 * 4);
  float* ffn   = (float*)alloc((size_t)Ntok * 768 * 4);
  float* yfl   = (float*)alloc((size_t)Ntok * 768 * 4);
  unsigned short* x16   = (unsigned short*)alloc((size_t)Ntok * 1536 * 2);
  unsigned short* yfl16 = (unsigned short*)alloc((size_t)Ntok * 1536 * 2);
  unsigned short* qr16  = (unsigned short*)alloc((size_t)24 * 1024 * 128 * 2);
  unsigned short* kr16  = (unsigned short*)alloc((size_t)24 * 1024 * 128 * 2);
  unsigned short* vr16  = (unsigned short*)alloc((size_t)24 * 64 * 2048 * 2);
  unsigned short* xb16  = (unsigned short*)alloc((size_t)Ec * CAPPc * 1536 * 2);
  unsigned short* wo16  = (unsigned short*)alloc((size_t)768 * 1536 * 2);
  unsigned short* xf16  = (unsigned short*)alloc((size_t)Ntok * 768 * 2);
  char* spb = alloc((size_t)24 * 1024 * 1024 * 4);          // 100.66 MB scores
  float* sp   = (float*)spb;
  float* gu   = (float*)spb;                                 // alias [0, 50.3M)
  float* yexp = (float*)spb;                                 // alias [0, 9.4M)
  unsigned short* act16 = (unsigned short*)(spb + 50331648); // alias [50.3M, 75.5M)
  unsigned short* wq16  = (unsigned short*)(spb + 75497472); // alias [75.5M, 82.6M)
  unsigned short* w13_16 = (unsigned short*)alloc((size_t)Ec * 4096 * 1536 * 2); // 100.66MB
  unsigned short* wt16   = w13_16;                           // alias (used after)
  unsigned short* w2_16  = (unsigned short*)alloc((size_t)Ec * 768 * 4096 * 2);  // 50.3MB
  int* top    = (int*)alloc(Ntok * 4);
  int* rankb  = (int*)alloc(Ntok * 4);
  int* cnt    = (int*)alloc(Lc * Ec * 4);
  float* psum = (float*)alloc(Lc * Ec * 4);
  float* z2   = (float*)alloc(Lc * 4);

  zero_small<<<1, 64, 0, stream>>>(psum, z2);
  embed_k<<<Ntok, 192, 0, stream>>>(idx, wte, x);

  for (int l = 0; l < Lc; ++l) {
    // weight + activation conversions for this layer
    split2_rows<<<(Ntok * 192 + 255) / 256, 256, 0, stream>>>(x, x16, 768, (long long)Ntok * 192);
    split2_wT<<<dim3(72, 24, 1), 256, 0, stream>>>(wqkv + (size_t)l * 768 * 2304, wq16,
                                                   768, 2304, 0, 0);
    split2_wT<<<dim3(24, 24, 1), 256, 0, stream>>>(oproj + (size_t)l * 768 * 768, wo16,
                                                   768, 768, 0, 0);
    split2_wT<<<dim3(128, 24, 8), 256, 0, stream>>>(w13 + (size_t)l * Ec * 768 * 4096, w13_16,
                                                    768, 4096, (long long)768 * 4096,
                                                    (long long)4096 * 1536);
    split2_wT<<<dim3(24, 64, 8), 256, 0, stream>>>(w2p + (size_t)l * Ec * 2048 * 768, w2_16,
                                                   2048, 768, (long long)2048 * 768,
                                                   (long long)768 * 4096);
    // qkv = x @ wqkv[l]
    gemm_h<128, 1, 0, 0, 0><<<288, 256, 0, stream>>>(
        x16, wq16, qkv, nullptr, 2048, 2304, 768, 2304, 16, 18, 0, 0, 1, 0, 0);
    rmsnorm_k<<<Ntok, 256, 0, stream>>>(qkv,       2304, qkv,       2304, qnw + l * 768);
    rmsnorm_k<<<Ntok, 256, 0, stream>>>(qkv + 768, 2304, qkv + 768, 2304, knw + l * 768);
    rope_split<<<(Ntok * 12 * 32) / 256, 256, 0, stream>>>(qkv, qr16, kr16, vr16);
    // scores = q @ k^T per (b,h), causal tile skip
    gemm_h<128, 1, 0, 0, 1><<<1536, 256, 0, stream>>>(
        qr16, kr16, sp, nullptr, 1024, 1024, 64, 1024, 8, 8,
        (long long)1024 * 128, (long long)1024 * 128, 1, (long long)1024 * 1024, 0);
    softmax_causal<<<dim3(1024, 24), 256, 0, stream>>>(sp);
    // y = P @ V  (P = sp reinterpreted as split-fp16)
    gemm_h<64, 1, 0, 0, 0><<<192, 256, 0, stream>>>(
        (const unsigned short*)sp, vr16, yfl, nullptr, 1024, 64, 1024, 768, 8, 1,
        (long long)1024 * 2048, (long long)64 * 2048, 12, (long long)1024 * 768, 64);
    split2_rows<<<(Ntok * 192 + 255) / 256, 256, 0, stream>>>(yfl, yfl16, 768,
                                                              (long long)Ntok * 192);
    // h = x + y @ o_proj[l]
    gemm_h<128, 1, 1, 0, 0><<<96, 256, 0, stream>>>(
        yfl16, wo16, hbuf, x, 2048, 768, 768, 768, 16, 6, 0, 0, 1, 0, 0);
    rmsnorm_k<<<Ntok, 256, 0, stream>>>(hbuf, 768, ffn, 768, ffnw + l * 768);
    gate_k<<<Ntok / 256, 256, 0, stream>>>(ffn, gatew + (size_t)l * 768 * 8, top,
                                           psum + l * 8, z2 + l);
    route_scan<<<1, 64, 0, stream>>>(top, rankb, cnt + l * 8);
    scatter_xb<<<Ntok, 192, 0, stream>>>(ffn, top, rankb, xb16);
    // gu = xb @ w13[l]  (batched over experts)
    gemm_h<128, 1, 0, 0, 0><<<768, 256, 0, stream>>>(
        xb16, w13_16, gu, nullptr, 384, 4096, 768, 4096, 3, 32,
        (long long)384 * 1536, (long long)4096 * 1536, 1, (long long)384 * 4096, 0);
    silu_k<<<(Ec * CAPPc * Hc) / 256, 256, 0, stream>>>(gu, act16);
    // yexp = act @ w2[l]
    gemm_h<64, 1, 0, 0, 0><<<288, 256, 0, stream>>>(
        act16, w2_16, yexp, nullptr, 384, 768, 2048, 768, 3, 12,
        (long long)384 * 4096, (long long)768 * 4096, 1, (long long)384 * 768, 0);
    gather_add<<<Ntok, 192, 0, stream>>>(hbuf, yexp, top, rankb, x);
  }

  rmsnorm_h<<<Ntok, 256, 0, stream>>>(x, xf16, lnf);
  f2h4<<<(int)(((long long)Vc * 768 / 4 + 255) / 256), 256, 0, stream>>>(
      wte, wt16, (long long)Vc * 768 / 4);
  // logits = xf @ wte^T  (single fp16, N tail handled)
  gemm_h<128, 0, 0, 1, 0><<<6288, 256, 0, stream>>>(
      xf16, wt16, out, nullptr, 2048, Vc, 768, Vc, 16, 393, 0, 0, 1, 0, 0);
  aux_fin<<<1, 64, 0, stream>>>(psum, cnt, z2, out + LOGITS_N);
}